// Round 1
// baseline (126.542 us; speedup 1.0000x reference)
//
#include <hip/hip_runtime.h>
#include <stdint.h>

// NormalizedLoss: batched chamfer + coverage/quality on point clouds.
// x: [32, 2048, 3] fp32, y: [32, 2048, 3] fp32 -> out: [val, cd, cov, qual] fp32.
//
// R16: keep R11's nn_kernel (measured session optimum) byte-identical, but
// fuse assemble into merge via the last-block pattern: each merge block
// writes its partials, __threadfence(), atomicAdd on a done-counter; the
// 512th arriver runs the assembly inline. The counter lives in poisoned ws,
// so nn_kernel (stream-previous) zeroes it -- no extra dispatch, no spin.
// Saves the 1-block assemble dispatch (~3us) + one launch gap (~2.5us).
// Budget recap: ~40us harness ws-poison fill (untouchable) + nn ~33 +
// merge2 ~6 + gaps.
//
// nn: 1024 blocks (side|b|pc(3)|qc(1)) x 512 thr, P=4 per lane, q staged in
// LDS as pair-records, 8-wave q-split, 4 blocks/CU = 32 waves/CU (max TLP).
// Inner loop: v_pk_fma_f32 x3 + v_min3_f32 with 11-bit q-index embedded in
// the distance mantissa (EMB) -> single float carries (d, argmin) lex order.
// Truncation ~1e-3 << 1.2e-2 threshold.

#define BB 32
#define NP 2048
#define BIGF 1e10f

typedef unsigned int u32;
typedef float f2 __attribute__((ext_vector_type(2)));

// embed 11-bit global q-index in the mantissa: float order ~ (d, idx) lex
#define EMB(d, jg) __uint_as_float((__float_as_uint(d) & 0xFFFFF800u) | (jg))

__device__ __forceinline__ f2 pk_fma(f2 a, f2 b, f2 c) {
  f2 d;
  asm("v_pk_fma_f32 %0, %1, %2, %3" : "=v"(d) : "v"(a), "v"(b), "v"(c));
  return d;
}
__device__ __forceinline__ float min3(float a, float b, float c) {
  float r;
  asm("v_min3_f32 %0, %1, %2, %3" : "=v"(r) : "v"(a), "v"(b), "v"(c));
  return r;
}

__global__ __launch_bounds__(512, 8) void nn_kernel(const float* __restrict__ x,
                                                    const float* __restrict__ y,
                                                    u32* __restrict__ part,
                                                    u32* __restrict__ done) {
  int bid = blockIdx.x;  // 1024 blocks: side(1)|b(5)|pc(3)|qc(1)
  int side = bid >> 9;
  int b = (bid >> 4) & 31;
  int pc = (bid >> 1) & 7;
  int qc = bid & 1;
  int tid = threadIdx.x;
  int w = __builtin_amdgcn_readfirstlane(tid >> 6);  // 0..7, wave-uniform
  int lane = tid & 63;

  // zero the merge2 arrival counter (ws is poisoned each iteration; this
  // kernel is stream-ordered before merge2, so kernel-end writeback makes
  // it visible there)
  if (bid == 0 && tid == 0) *done = 0u;

  __shared__ float4 qs[1024];     // 16KB; rec r -> qs[2r]=(x0,x1,y0,y1), qs[2r+1]=(z0,z1,n0,n1)
  __shared__ u32 merged[8][256];  // 8KB per-wave embedded (d|idx) partials

  // ---- stage this block's 1024 q (qc half); 2 points per thread ----
  {
    const float* qraw = (side ? x : y) + (b * NP + qc * 1024) * 3 + tid * 6;
    f2 a01 = *(const f2*)(qraw);      // x0,y0
    f2 a23 = *(const f2*)(qraw + 2);  // z0,x1
    f2 a45 = *(const f2*)(qraw + 4);  // y1,z1
    float q0x = a01.x, q0y = a01.y, q0z = a23.x;
    float q1x = a23.y, q1y = a45.x, q1z = a45.y;
    float n0 = q0x * q0x + q0y * q0y + q0z * q0z;
    float n1 = q1x * q1x + q1y * q1y + q1z * q1z;
    if (q0x + q0y + q0z == 0.f) n0 += BIGF;  // invalid rows out of every min
    if (q1x + q1y + q1z == 0.f) n1 += BIGF;
    qs[2 * tid]     = make_float4(q0x, q1x, q0y, q1y);
    qs[2 * tid + 1] = make_float4(q0z, q1z, n0, n1);
  }

  // ---- p prologue: every wave loads the SAME 256 p; -2p dup'd into f2 ----
  const float* praw = (side ? y : x) + (b * NP + pc * 256) * 3;
  f2 pmx[4], pmy[4], pmz[4];
  float best[4];
#pragma unroll
  for (int k = 0; k < 4; ++k) {
    int pl = lane + 64 * k;
    float p0 = praw[3 * pl], p1 = praw[3 * pl + 1], p2 = praw[3 * pl + 2];
    pmx[k] = (f2){-2.f * p0, -2.f * p0};
    pmy[k] = (f2){-2.f * p1, -2.f * p1};
    pmz[k] = (f2){-2.f * p2, -2.f * p2};
    best[k] = 3.0e38f;
  }
  __syncthreads();

  // ---- inner loop: wave's 64 records (128 q) vs its 4 p-points ----
  const float4* qr = &qs[w * 128];
  u32 je = (u32)(qc * 1024 + w * 128);  // global q index of this wave's rec 0
#pragma unroll 8
  for (int r = 0; r < 64; ++r) {
    float4 A = qr[2 * r];      // wave-uniform ds_read_b128 (broadcast)
    float4 B = qr[2 * r + 1];
    f2 qx2 = (f2){A.x, A.y};
    f2 qy2 = (f2){A.z, A.w};
    f2 qz2 = (f2){B.x, B.y};
    f2 qw2 = (f2){B.z, B.w};
    u32 jg = je + 2 * (u32)r, jg1 = jg + 1;
#pragma unroll
    for (int k = 0; k < 4; ++k) {
      f2 d2 = pk_fma(qx2, pmx[k], pk_fma(qy2, pmy[k], pk_fma(qz2, pmz[k], qw2)));
      best[k] = min3(best[k], EMB(d2.x, jg), EMB(d2.y, jg1));
    }
  }

  merged[w][lane +   0] = __float_as_uint(best[0]);
  merged[w][lane +  64] = __float_as_uint(best[1]);
  merged[w][lane + 128] = __float_as_uint(best[2]);
  merged[w][lane + 192] = __float_as_uint(best[3]);
  __syncthreads();

  // ---- merge 8 wave partials; store embedded u32 per p ----
  if (tid < 256) {
    float bd = __uint_as_float(merged[0][tid]);
#pragma unroll
    for (int ww = 1; ww < 8; ++ww) bd = fminf(bd, __uint_as_float(merged[ww][tid]));
    // part[qc][side*65536 + b*2048 + pc*256 + tid]
    part[qc * 131072 + side * 65536 + b * 2048 + pc * 256 + tid] = __float_as_uint(bd);
  }
}

// 512 blocks x 256 thr: combine qc halves, recompute pn/validity, scatter
// hits into a block-local bitmask, reduce sums/cnts per block. The LAST
// block to finish (device-scope arrival counter) then assembles the 4
// output scalars inline -- replaces the former 1-block assemble kernel.
__global__ __launch_bounds__(256) void merge2_kernel(const float* __restrict__ x,
                                                     const float* __restrict__ y,
                                                     const u32* __restrict__ part,
                                                     u32* __restrict__ hitpart,
                                                     float* __restrict__ sums_part,
                                                     float* __restrict__ cnts_part,
                                                     u32* __restrict__ done,
                                                     float* __restrict__ out) {
  int bid = blockIdx.x;  // 512: side(1)|b(5)|pc(3)
  int side = bid >> 8;
  int b = (bid >> 3) & 31;
  int pc = bid & 7;
  int tid = threadIdx.x;
  int lane = tid & 63, w = tid >> 6;

  __shared__ u32 hitlds[64];
  __shared__ float redc[4], redn[4];
  __shared__ int lastflag;
  if (tid < 64) hitlds[tid] = 0u;
  __syncthreads();

  int pidx = side * 65536 + b * 2048 + pc * 256 + tid;
  float bd = fminf(__uint_as_float(part[pidx]), __uint_as_float(part[131072 + pidx]));
  u32 bits = __float_as_uint(bd);
  u32 bi = bits & 0x7FFu;                            // global q index
  float dmin = __uint_as_float(bits & 0xFFFFF800u);  // truncated min d'
  const float* praw = (side ? y : x) + (b * NP + pc * 256 + tid) * 3;
  float p0 = praw[0], p1 = praw[1], p2 = praw[2];
  bool valid = (p0 + p1 + p2) != 0.f;
  float contrib = valid ? (dmin + p0 * p0 + p1 * p1 + p2 * p2) : 0.f;
  float cnt = valid ? 1.f : 0.f;
  if (valid) atomicOr(&hitlds[bi >> 5], 1u << (bi & 31));

  for (int o = 32; o > 0; o >>= 1) {
    contrib += __shfl_down(contrib, o, 64);
    cnt += __shfl_down(cnt, o, 64);
  }
  if (lane == 0) { redc[w] = contrib; redn[w] = cnt; }
  __syncthreads();
  if (tid == 0) {
    sums_part[bid] = redc[0] + redc[1] + redc[2] + redc[3];
    cnts_part[bid] = redn[0] + redn[1] + redn[2] + redn[3];
  }
  if (tid < 64) hitpart[bid * 64 + tid] = hitlds[tid];

  // ---- arrival: release partials, count in; last block assembles ----
  __threadfence();   // release: write back this block's partials (cross-XCD)
  __syncthreads();   // all threads' writes issued+fenced before the signal
  if (tid == 0) lastflag = (atomicAdd(done, 1u) == 511u);
  __syncthreads();
  if (!lastflag) return;
  __threadfence();   // acquire: invalidate local caches before reading others'

  // ---- assemble with this block's 256 threads: 4 threads per (side,b) ----
  __shared__ float hs[64], ss[64], cs[64];
  int sb = tid >> 2, c = tid & 3;  // sb = side*32+b; part bid = sb*8 + pc
  float h = 0.f;
  for (int wd = c; wd < 64; wd += 4) {
    u32 m = 0u;
#pragma unroll
    for (int blk = 0; blk < 8; ++blk) m |= hitpart[(sb * 8 + blk) * 64 + wd];
    h += (float)__popc(m);
  }
  h += __shfl_down(h, 2, 4);
  h += __shfl_down(h, 1, 4);
  if (c == 0) {
    float s = 0.f, n = 0.f;
#pragma unroll
    for (int blk = 0; blk < 8; ++blk) {
      s += sums_part[sb * 8 + blk];
      n += cnts_part[sb * 8 + blk];
    }
    hs[sb] = h; ss[sb] = s; cs[sb] = n;
  }
  __syncthreads();
  if (tid < 64) {
    float cd = 0.f, cov = 0.f, qual = 0.f;
    if (tid < BB) {
      float nx = cs[tid], ny = cs[BB + tid];
      cd = ss[tid] / nx + ss[BB + tid] / ny;
      cov = hs[tid] / ny;        // side0 (p=x) hits y indices: /ny
      qual = hs[BB + tid] / nx;  // side1 (p=y) hits x indices: /nx
    }
    for (int o = 32; o > 0; o >>= 1) {
      cd += __shfl_down(cd, o, 64);
      cov += __shfl_down(cov, o, 64);
      qual += __shfl_down(qual, o, 64);
    }
    if (tid == 0) {
      cd /= (float)BB; cov /= (float)BB; qual /= (float)BB;
      out[0] = cd - 1e-4f * cov - 1e-4f * qual;  // WCD*cd - WCOV*cov - WQUAL*qual
      out[1] = cd;
      out[2] = cov;
      out[3] = qual;
    }
  }
}

extern "C" void kernel_launch(void* const* d_in, const int* in_sizes, int n_in,
                              void* d_out, int out_size, void* d_ws, size_t ws_size,
                              hipStream_t stream) {
  const float* x = (const float*)d_in[0];
  const float* y = (const float*)d_in[1];
  float* out = (float*)d_out;
  char* ws = (char*)d_ws;

  // ws layout (all regions fully written by producers before use; the
  // arrival counter is zeroed by nn_kernel each iteration):
  //   [0, 128KB)        hitpart: 512 blocks x 64 u32
  //   [128KB, +2KB)     sums_part: 512 f32
  //   [130KB, +2KB)     cnts_part: 512 f32
  //   [132KB, +1MB)     part: 2 qc x 131072 u32 embedded (d|idx)
  //   [132KB+1MB, +4B)  done: merge2 arrival counter
  u32* hitpart = (u32*)ws;
  float* sums_part = (float*)(ws + 131072);
  float* cnts_part = (float*)(ws + 133120);
  u32* part = (u32*)(ws + 135168);
  u32* done = (u32*)(ws + 135168 + 1048576);

  nn_kernel<<<1024, 512, 0, stream>>>(x, y, part, done);
  merge2_kernel<<<512, 256, 0, stream>>>(x, y, part, hitpart, sums_part, cnts_part, done, out);
}

// Round 2
// 89.449 us; speedup vs baseline: 1.4147x; 1.4147x over previous
//
#include <hip/hip_runtime.h>
#include <stdint.h>

// NormalizedLoss: batched chamfer + coverage/quality on point clouds.
// x: [32, 2048, 3] fp32, y: [32, 2048, 3] fp32 -> out: [val, cd, cov, qual] fp32.
//
// R17: nn_kernel stays R11-identical (measured session optimum). The merge+
// assemble pair is replaced by ONE fence-free kernel exploiting linearity:
// every output is a mean over (side,b) of a closed-form block-local term
//   cd term   = ss/n_p            (ss = sum of min-d over valid p)
//   cov/qual  = hits/n_q          (hits = popcount of q-index bitmask)
// so one block per (side,b) (64 blocks x 1024 thr) computes its term with a
// block-LOCAL hit bitmask and atomicAdd's the scaled contribution into out.
// No __threadfence (R16's 41us stall: 2048 waves x buffer_wbl2 L2-maintenance
// serialization), no arrival counter, no hitpart/sums/cnts HBM round-trip.
// nn_kernel zeroes out[0..4) (stream-ordered before the atomics).
// Budget: ~40us harness ws-poison fill (untouchable) + nn ~33 + merge3 ~5
// + 2 launch gaps.
//
// nn: 1024 blocks (side|b|pc(3)|qc(1)) x 512 thr, P=4 per lane, q staged in
// LDS as pair-records, 8-wave q-split, 4 blocks/CU = 32 waves/CU (max TLP).
// Inner loop: v_pk_fma_f32 x3 + v_min3_f32 with 11-bit q-index embedded in
// the distance mantissa (EMB) -> single float carries (d, argmin) lex order.
// Truncation ~1e-3 << 1.2e-2 threshold.

#define BB 32
#define NP 2048
#define BIGF 1e10f

typedef unsigned int u32;
typedef float f2 __attribute__((ext_vector_type(2)));

// embed 11-bit global q-index in the mantissa: float order ~ (d, idx) lex
#define EMB(d, jg) __uint_as_float((__float_as_uint(d) & 0xFFFFF800u) | (jg))

__device__ __forceinline__ f2 pk_fma(f2 a, f2 b, f2 c) {
  f2 d;
  asm("v_pk_fma_f32 %0, %1, %2, %3" : "=v"(d) : "v"(a), "v"(b), "v"(c));
  return d;
}
__device__ __forceinline__ float min3(float a, float b, float c) {
  float r;
  asm("v_min3_f32 %0, %1, %2, %3" : "=v"(r) : "v"(a), "v"(b), "v"(c));
  return r;
}

__global__ __launch_bounds__(512, 8) void nn_kernel(const float* __restrict__ x,
                                                    const float* __restrict__ y,
                                                    u32* __restrict__ part,
                                                    float* __restrict__ out) {
  int bid = blockIdx.x;  // 1024 blocks: side(1)|b(5)|pc(3)|qc(1)
  int side = bid >> 9;
  int b = (bid >> 4) & 31;
  int pc = (bid >> 1) & 7;
  int qc = bid & 1;
  int tid = threadIdx.x;
  int w = __builtin_amdgcn_readfirstlane(tid >> 6);  // 0..7, wave-uniform
  int lane = tid & 63;

  // zero the output accumulators (merge3 atomicAdds into them; stream order
  // + kernel-end writeback makes this visible to merge3's atomics)
  if (bid == 0 && tid < 4) out[tid] = 0.f;

  __shared__ float4 qs[1024];     // 16KB; rec r -> qs[2r]=(x0,x1,y0,y1), qs[2r+1]=(z0,z1,n0,n1)
  __shared__ u32 merged[8][256];  // 8KB per-wave embedded (d|idx) partials

  // ---- stage this block's 1024 q (qc half); 2 points per thread ----
  {
    const float* qraw = (side ? x : y) + (b * NP + qc * 1024) * 3 + tid * 6;
    f2 a01 = *(const f2*)(qraw);      // x0,y0
    f2 a23 = *(const f2*)(qraw + 2);  // z0,x1
    f2 a45 = *(const f2*)(qraw + 4);  // y1,z1
    float q0x = a01.x, q0y = a01.y, q0z = a23.x;
    float q1x = a23.y, q1y = a45.x, q1z = a45.y;
    float n0 = q0x * q0x + q0y * q0y + q0z * q0z;
    float n1 = q1x * q1x + q1y * q1y + q1z * q1z;
    if (q0x + q0y + q0z == 0.f) n0 += BIGF;  // invalid rows out of every min
    if (q1x + q1y + q1z == 0.f) n1 += BIGF;
    qs[2 * tid]     = make_float4(q0x, q1x, q0y, q1y);
    qs[2 * tid + 1] = make_float4(q0z, q1z, n0, n1);
  }

  // ---- p prologue: every wave loads the SAME 256 p; -2p dup'd into f2 ----
  const float* praw = (side ? y : x) + (b * NP + pc * 256) * 3;
  f2 pmx[4], pmy[4], pmz[4];
  float best[4];
#pragma unroll
  for (int k = 0; k < 4; ++k) {
    int pl = lane + 64 * k;
    float p0 = praw[3 * pl], p1 = praw[3 * pl + 1], p2 = praw[3 * pl + 2];
    pmx[k] = (f2){-2.f * p0, -2.f * p0};
    pmy[k] = (f2){-2.f * p1, -2.f * p1};
    pmz[k] = (f2){-2.f * p2, -2.f * p2};
    best[k] = 3.0e38f;
  }
  __syncthreads();

  // ---- inner loop: wave's 64 records (128 q) vs its 4 p-points ----
  const float4* qr = &qs[w * 128];
  u32 je = (u32)(qc * 1024 + w * 128);  // global q index of this wave's rec 0
#pragma unroll 8
  for (int r = 0; r < 64; ++r) {
    float4 A = qr[2 * r];      // wave-uniform ds_read_b128 (broadcast)
    float4 B = qr[2 * r + 1];
    f2 qx2 = (f2){A.x, A.y};
    f2 qy2 = (f2){A.z, A.w};
    f2 qz2 = (f2){B.x, B.y};
    f2 qw2 = (f2){B.z, B.w};
    u32 jg = je + 2 * (u32)r, jg1 = jg + 1;
#pragma unroll
    for (int k = 0; k < 4; ++k) {
      f2 d2 = pk_fma(qx2, pmx[k], pk_fma(qy2, pmy[k], pk_fma(qz2, pmz[k], qw2)));
      best[k] = min3(best[k], EMB(d2.x, jg), EMB(d2.y, jg1));
    }
  }

  merged[w][lane +   0] = __float_as_uint(best[0]);
  merged[w][lane +  64] = __float_as_uint(best[1]);
  merged[w][lane + 128] = __float_as_uint(best[2]);
  merged[w][lane + 192] = __float_as_uint(best[3]);
  __syncthreads();

  // ---- merge 8 wave partials; store embedded u32 per p ----
  if (tid < 256) {
    float bd = __uint_as_float(merged[0][tid]);
#pragma unroll
    for (int ww = 1; ww < 8; ++ww) bd = fminf(bd, __uint_as_float(merged[ww][tid]));
    // part[qc][side*65536 + b*2048 + pc*256 + tid]
    part[qc * 131072 + side * 65536 + b * 2048 + pc * 256 + tid] = __float_as_uint(bd);
  }
}

// 64 blocks x 1024 thr: one block per (side,b). Combine qc halves, recompute
// p-norm/validity, build the (block-local) 2048-bit q hit bitmask in LDS,
// count valid q, then atomicAdd the closed-form per-(side,b) contribution
// into out[]. Linearity of all four outputs over (side,b) terms makes this
// exact (modulo fp-add order, ~1e-7): 
//   out[1] cd   += (ss/n_p)/32            (both sides)
//   out[2] cov  += (hits/n_q)/32          (side 0: p=x, q=y)
//   out[3] qual += (hits/n_q)/32          (side 1: p=y, q=x)
//   out[0] val  += (ss/n_p - 1e-4*hits/n_q)/32
__global__ __launch_bounds__(1024) void merge3_kernel(const float* __restrict__ x,
                                                      const float* __restrict__ y,
                                                      const u32* __restrict__ part,
                                                      float* __restrict__ out) {
  int bid = blockIdx.x;  // 64: side(1)|b(5)
  int side = bid >> 5;
  int b = bid & 31;
  int tid = threadIdx.x;
  int lane = tid & 63, w = tid >> 6;  // 16 waves

  __shared__ u32 hitlds[64];          // 2048-bit q hit bitmask
  __shared__ float redc[16], redn[16], redq[16];
  if (tid < 64) hitlds[tid] = 0u;
  __syncthreads();

  const float* praw = (side ? y : x) + b * NP * 3;
  const float* qraw = (side ? x : y) + b * NP * 3;

  float contrib = 0.f, cnt = 0.f, qcnt = 0.f;
#pragma unroll
  for (int k = 0; k < 2; ++k) {
    int pi = tid + k * 1024;
    int pidx = side * 65536 + b * 2048 + pi;
    float bd = fminf(__uint_as_float(part[pidx]), __uint_as_float(part[131072 + pidx]));
    u32 bits = __float_as_uint(bd);
    u32 bi = bits & 0x7FFu;                            // global q index
    float dmin = __uint_as_float(bits & 0xFFFFF800u);  // truncated min d'
    float p0 = praw[3 * pi], p1 = praw[3 * pi + 1], p2 = praw[3 * pi + 2];
    if (p0 + p1 + p2 != 0.f) {
      contrib += dmin + p0 * p0 + p1 * p1 + p2 * p2;
      cnt += 1.f;
      atomicOr(&hitlds[bi >> 5], 1u << (bi & 31));
    }
    float q0 = qraw[3 * pi], q1 = qraw[3 * pi + 1], q2 = qraw[3 * pi + 2];
    if (q0 + q1 + q2 != 0.f) qcnt += 1.f;
  }

  for (int o = 32; o > 0; o >>= 1) {
    contrib += __shfl_down(contrib, o, 64);
    cnt += __shfl_down(cnt, o, 64);
    qcnt += __shfl_down(qcnt, o, 64);
  }
  if (lane == 0) { redc[w] = contrib; redn[w] = cnt; redq[w] = qcnt; }
  __syncthreads();

  if (tid < 64) {  // wave 0: popcount bitmask + final combine
    float h = (float)__popc(hitlds[tid]);
    for (int o = 32; o > 0; o >>= 1) h += __shfl_down(h, o, 64);
    if (tid == 0) {
      float s = 0.f, n = 0.f, nq = 0.f;
#pragma unroll
      for (int i = 0; i < 16; ++i) { s += redc[i]; n += redn[i]; nq += redq[i]; }
      float cdt = s / n;       // this side's mean-min-distance term
      float hqt = h / nq;      // hit fraction of q indices
      const float inv = 1.f / (float)BB;
      atomicAdd(out + 1, cdt * inv);
      atomicAdd(out + 2 + side, hqt * inv);
      atomicAdd(out + 0, (cdt - 1e-4f * hqt) * inv);
    }
  }
}

extern "C" void kernel_launch(void* const* d_in, const int* in_sizes, int n_in,
                              void* d_out, int out_size, void* d_ws, size_t ws_size,
                              hipStream_t stream) {
  const float* x = (const float*)d_in[0];
  const float* y = (const float*)d_in[1];
  float* out = (float*)d_out;
  char* ws = (char*)d_ws;

  // ws layout: [0, 1MB) part: 2 qc x 131072 u32 embedded (d|idx).
  // Fully written by nn_kernel before merge3 reads it; no memset needed.
  u32* part = (u32*)ws;

  nn_kernel<<<1024, 512, 0, stream>>>(x, y, part, out);
  merge3_kernel<<<64, 1024, 0, stream>>>(x, y, part, out);
}

// Round 3
// 85.679 us; speedup vs baseline: 1.4769x; 1.0440x over previous
//
#include <hip/hip_runtime.h>
#include <stdint.h>

// NormalizedLoss: batched chamfer + coverage/quality on point clouds.
// x: [32, 2048, 3] fp32, y: [32, 2048, 3] fp32 -> out: [val, cd, cov, qual] fp32.
//
// R18: R17 structure (fence-free 2-kernel, measured 89.4us) + single-
// instruction index embed. (d & 0xFFFFF800) | jg was 2 VOP2s (v_and literal
// + v_or sgpr); v_bfi_b32 mask,d,jg computes (mask&d)|(~mask&jg) == embed in
// ONE VALU op with mask in a hoisted VGPR and jg in SGPR (1 sgpr read -
// legal). Inner loop: 32 -> 24 VALU per record-group (-25% static VALU).
// Budget: ~40us harness ws-poison fill (untouchable) + nn ~33 (target ~29)
// + merge3 ~4 + 2 launch gaps.
//
// nn: 1024 blocks (side|b|pc(3)|qc(1)) x 512 thr, P=4 per lane, q staged in
// LDS as pair-records, 8-wave q-split, 4 blocks/CU = 32 waves/CU (max TLP).
// Inner loop: v_pk_fma_f32 x3 + v_bfi_b32 x2 + v_min3_f32; 11-bit q-index
// embedded in the distance mantissa -> single float carries (d, argmin) lex
// order. Truncation ~1e-3 << 1.2e-2 threshold.

#define BB 32
#define NP 2048
#define BIGF 1e10f

typedef unsigned int u32;
typedef float f2 __attribute__((ext_vector_type(2)));

__device__ __forceinline__ f2 pk_fma(f2 a, f2 b, f2 c) {
  f2 d;
  asm("v_pk_fma_f32 %0, %1, %2, %3" : "=v"(d) : "v"(a), "v"(b), "v"(c));
  return d;
}
__device__ __forceinline__ float min3(float a, float b, float c) {
  float r;
  asm("v_min3_f32 %0, %1, %2, %3" : "=v"(r) : "v"(a), "v"(b), "v"(c));
  return r;
}
// (maskv & d) | (~maskv & jg) with maskv=0xFFFFF800 -> embed jg in low 11 bits
__device__ __forceinline__ float emb(float d, u32 jg, u32 maskv) {
  float r;
  asm("v_bfi_b32 %0, %1, %2, %3" : "=v"(r) : "v"(maskv), "v"(d), "s"(jg));
  return r;
}

__global__ __launch_bounds__(512, 8) void nn_kernel(const float* __restrict__ x,
                                                    const float* __restrict__ y,
                                                    u32* __restrict__ part,
                                                    float* __restrict__ out) {
  int bid = blockIdx.x;  // 1024 blocks: side(1)|b(5)|pc(3)|qc(1)
  int side = bid >> 9;
  int b = (bid >> 4) & 31;
  int pc = (bid >> 1) & 7;
  int qc = bid & 1;
  int tid = threadIdx.x;
  int w = __builtin_amdgcn_readfirstlane(tid >> 6);  // 0..7, wave-uniform
  int lane = tid & 63;

  // zero the output accumulators (merge3 atomicAdds into them; stream order
  // + kernel-end writeback makes this visible to merge3's atomics)
  if (bid == 0 && tid < 4) out[tid] = 0.f;

  __shared__ float4 qs[1024];     // 16KB; rec r -> qs[2r]=(x0,x1,y0,y1), qs[2r+1]=(z0,z1,n0,n1)
  __shared__ u32 merged[8][256];  // 8KB per-wave embedded (d|idx) partials

  // ---- stage this block's 1024 q (qc half); 2 points per thread ----
  {
    const float* qraw = (side ? x : y) + (b * NP + qc * 1024) * 3 + tid * 6;
    f2 a01 = *(const f2*)(qraw);      // x0,y0
    f2 a23 = *(const f2*)(qraw + 2);  // z0,x1
    f2 a45 = *(const f2*)(qraw + 4);  // y1,z1
    float q0x = a01.x, q0y = a01.y, q0z = a23.x;
    float q1x = a23.y, q1y = a45.x, q1z = a45.y;
    float n0 = q0x * q0x + q0y * q0y + q0z * q0z;
    float n1 = q1x * q1x + q1y * q1y + q1z * q1z;
    if (q0x + q0y + q0z == 0.f) n0 += BIGF;  // invalid rows out of every min
    if (q1x + q1y + q1z == 0.f) n1 += BIGF;
    qs[2 * tid]     = make_float4(q0x, q1x, q0y, q1y);
    qs[2 * tid + 1] = make_float4(q0z, q1z, n0, n1);
  }

  // ---- p prologue: every wave loads the SAME 256 p; -2p dup'd into f2 ----
  const float* praw = (side ? y : x) + (b * NP + pc * 256) * 3;
  f2 pmx[4], pmy[4], pmz[4];
  float best[4];
#pragma unroll
  for (int k = 0; k < 4; ++k) {
    int pl = lane + 64 * k;
    float p0 = praw[3 * pl], p1 = praw[3 * pl + 1], p2 = praw[3 * pl + 2];
    pmx[k] = (f2){-2.f * p0, -2.f * p0};
    pmy[k] = (f2){-2.f * p1, -2.f * p1};
    pmz[k] = (f2){-2.f * p2, -2.f * p2};
    best[k] = 3.0e38f;
  }
  __syncthreads();

  // ---- inner loop: wave's 64 records (128 q) vs its 4 p-points ----
  const float4* qr = &qs[w * 128];
  u32 je = (u32)(qc * 1024 + w * 128);  // global q index of this wave's rec 0
  const u32 mv = 0xFFFFF800u;           // loop-invariant embed mask (VGPR)
#pragma unroll 8
  for (int r = 0; r < 64; ++r) {
    float4 A = qr[2 * r];      // wave-uniform ds_read_b128 (broadcast)
    float4 B = qr[2 * r + 1];
    f2 qx2 = (f2){A.x, A.y};
    f2 qy2 = (f2){A.z, A.w};
    f2 qz2 = (f2){B.x, B.y};
    f2 qw2 = (f2){B.z, B.w};
    u32 jg = je + 2 * (u32)r, jg1 = jg + 1;  // wave-uniform (SGPR, scalar pipe)
#pragma unroll
    for (int k = 0; k < 4; ++k) {
      f2 d2 = pk_fma(qx2, pmx[k], pk_fma(qy2, pmy[k], pk_fma(qz2, pmz[k], qw2)));
      best[k] = min3(best[k], emb(d2.x, jg, mv), emb(d2.y, jg1, mv));
    }
  }

  merged[w][lane +   0] = __float_as_uint(best[0]);
  merged[w][lane +  64] = __float_as_uint(best[1]);
  merged[w][lane + 128] = __float_as_uint(best[2]);
  merged[w][lane + 192] = __float_as_uint(best[3]);
  __syncthreads();

  // ---- merge 8 wave partials; store embedded u32 per p ----
  if (tid < 256) {
    float bd = __uint_as_float(merged[0][tid]);
#pragma unroll
    for (int ww = 1; ww < 8; ++ww) bd = fminf(bd, __uint_as_float(merged[ww][tid]));
    // part[qc][side*65536 + b*2048 + pc*256 + tid]
    part[qc * 131072 + side * 65536 + b * 2048 + pc * 256 + tid] = __float_as_uint(bd);
  }
}

// 64 blocks x 1024 thr: one block per (side,b). Combine qc halves, recompute
// p-norm/validity, build the (block-local) 2048-bit q hit bitmask in LDS,
// count valid q, then atomicAdd the closed-form per-(side,b) contribution
// into out[]. Linearity of all four outputs over (side,b) terms makes this
// exact (modulo fp-add order, ~1e-7):
//   out[1] cd   += (ss/n_p)/32            (both sides)
//   out[2] cov  += (hits/n_q)/32          (side 0: p=x, q=y)
//   out[3] qual += (hits/n_q)/32          (side 1: p=y, q=x)
//   out[0] val  += (ss/n_p - 1e-4*hits/n_q)/32
__global__ __launch_bounds__(1024) void merge3_kernel(const float* __restrict__ x,
                                                      const float* __restrict__ y,
                                                      const u32* __restrict__ part,
                                                      float* __restrict__ out) {
  int bid = blockIdx.x;  // 64: side(1)|b(5)
  int side = bid >> 5;
  int b = bid & 31;
  int tid = threadIdx.x;
  int lane = tid & 63, w = tid >> 6;  // 16 waves

  __shared__ u32 hitlds[64];          // 2048-bit q hit bitmask
  __shared__ float redc[16], redn[16], redq[16];
  if (tid < 64) hitlds[tid] = 0u;
  __syncthreads();

  const float* praw = (side ? y : x) + b * NP * 3;
  const float* qraw = (side ? x : y) + b * NP * 3;

  float contrib = 0.f, cnt = 0.f, qcnt = 0.f;
#pragma unroll
  for (int k = 0; k < 2; ++k) {
    int pi = tid + k * 1024;
    int pidx = side * 65536 + b * 2048 + pi;
    float bd = fminf(__uint_as_float(part[pidx]), __uint_as_float(part[131072 + pidx]));
    u32 bits = __float_as_uint(bd);
    u32 bi = bits & 0x7FFu;                            // global q index
    float dmin = __uint_as_float(bits & 0xFFFFF800u);  // truncated min d'
    float p0 = praw[3 * pi], p1 = praw[3 * pi + 1], p2 = praw[3 * pi + 2];
    if (p0 + p1 + p2 != 0.f) {
      contrib += dmin + p0 * p0 + p1 * p1 + p2 * p2;
      cnt += 1.f;
      atomicOr(&hitlds[bi >> 5], 1u << (bi & 31));
    }
    float q0 = qraw[3 * pi], q1 = qraw[3 * pi + 1], q2 = qraw[3 * pi + 2];
    if (q0 + q1 + q2 != 0.f) qcnt += 1.f;
  }

  for (int o = 32; o > 0; o >>= 1) {
    contrib += __shfl_down(contrib, o, 64);
    cnt += __shfl_down(cnt, o, 64);
    qcnt += __shfl_down(qcnt, o, 64);
  }
  if (lane == 0) { redc[w] = contrib; redn[w] = cnt; redq[w] = qcnt; }
  __syncthreads();

  if (tid < 64) {  // wave 0: popcount bitmask + final combine
    float h = (float)__popc(hitlds[tid]);
    for (int o = 32; o > 0; o >>= 1) h += __shfl_down(h, o, 64);
    if (tid == 0) {
      float s = 0.f, n = 0.f, nq = 0.f;
#pragma unroll
      for (int i = 0; i < 16; ++i) { s += redc[i]; n += redn[i]; nq += redq[i]; }
      float cdt = s / n;       // this side's mean-min-distance term
      float hqt = h / nq;      // hit fraction of q indices
      const float inv = 1.f / (float)BB;
      atomicAdd(out + 1, cdt * inv);
      atomicAdd(out + 2 + side, hqt * inv);
      atomicAdd(out + 0, (cdt - 1e-4f * hqt) * inv);
    }
  }
}

extern "C" void kernel_launch(void* const* d_in, const int* in_sizes, int n_in,
                              void* d_out, int out_size, void* d_ws, size_t ws_size,
                              hipStream_t stream) {
  const float* x = (const float*)d_in[0];
  const float* y = (const float*)d_in[1];
  float* out = (float*)d_out;
  char* ws = (char*)d_ws;

  // ws layout: [0, 1MB) part: 2 qc x 131072 u32 embedded (d|idx).
  // Fully written by nn_kernel before merge3 reads it; no memset needed.
  u32* part = (u32*)ws;

  nn_kernel<<<1024, 512, 0, stream>>>(x, y, part, out);
  merge3_kernel<<<64, 1024, 0, stream>>>(x, y, part, out);
}